// Round 1
// baseline (285.396 us; speedup 1.0000x reference)
//
#include <hip/hip_runtime.h>

#define BB 16
#define CC 256
#define NN 1024

typedef _Float16 f16;
typedef __attribute__((ext_vector_type(8))) _Float16 half8;   // MFMA A/B frag (4 VGPRs)
typedef __attribute__((ext_vector_type(4))) float f32x4;      // MFMA C/D frag

__device__ __forceinline__ half8 ldg8(const f16* p) {
  return *reinterpret_cast<const half8*>(p);
}

// ---------------- weight pack: W fp32 [ci][co] -> frag-packed f16 wp[(ct*8+kc)*512 + lane*8] ----
struct WP5 {
  const float* s[5];
  f16* d[5];
};

__global__ void __launch_bounds__(256) k_packW(WP5 p) {
  __shared__ float ws[256][17];
  int m = blockIdx.y, ct = blockIdx.x;
  const float* W = p.s[m];
  f16* wp = p.d[m];
  int tid = threadIdx.x;
  int col = tid & 15, cig = tid >> 4;
#pragma unroll
  for (int pg = 0; pg < 16; ++pg) {
    int ci = pg * 16 + cig;
    ws[ci][col] = W[(size_t)ci * 256 + ct * 16 + col];
  }
  __syncthreads();
  int lane = tid & 63, wave = tid >> 6;
  int row16 = lane & 15, quad = lane >> 4;
#pragma unroll
  for (int kk = 0; kk < 2; ++kk) {
    int kc = wave * 2 + kk;
    half8 o;
#pragma unroll
    for (int j = 0; j < 8; ++j) o[j] = (f16)ws[kc * 32 + quad * 8 + j][row16];
    *reinterpret_cast<half8*>(wp + ((size_t)ct * 8 + kc) * 512 + lane * 8) = o;
  }
}

// ---------------- QKV: x fp32 [bg][c][n] -> frag-packed q,k,vT (unchanged) ----------------
struct QkvSmem {
  union {
    struct { f16 hi[32][264]; f16 lo[32][264]; } ts;
    f16 ex[2][16][264];
    f16 exv[256][40];
  };
};

__global__ void __launch_bounds__(256) k_qkv(const float* __restrict__ x,
    const f16* __restrict__ wqp, const f16* __restrict__ wkp, const f16* __restrict__ wvp,
    const float* __restrict__ bq, const float* __restrict__ bk, const float* __restrict__ bv,
    f16* __restrict__ qp, f16* __restrict__ kp, f16* __restrict__ vp, int b_base) {
  __shared__ QkvSmem sm;
  int z = blockIdx.z;
  const f16* WT     = (z == 0) ? wqp : (z == 1) ? wkp : wvp;
  const float* bias = (z == 0) ? bq  : (z == 1) ? bk  : bv;
  int bl = blockIdx.x, bg = b_base + bl, n0 = blockIdx.y * 32;
  int tid = threadIdx.x, wave = tid >> 6, lane = tid & 63;
  int row16 = lane & 15, quad = lane >> 4;
  int g = wave >> 1, h = wave & 1;

#pragma unroll
  for (int e = tid; e < 2048; e += 256) {
    int c = e >> 3, n4 = (e & 7) << 2;
    float4 u = *reinterpret_cast<const float4*>(x + (size_t)(bg * CC + c) * NN + n0 + n4);
    float uv[4] = {u.x, u.y, u.z, u.w};
#pragma unroll
    for (int i = 0; i < 4; ++i) {
      f16 hh = (f16)uv[i];
      sm.ts.hi[n4 + i][c] = hh;
      sm.ts.lo[n4 + i][c] = (f16)(uv[i] - (float)hh);
    }
  }
  __syncthreads();

  half8 ah[8], al[8];
#pragma unroll
  for (int kc = 0; kc < 8; ++kc) {
    ah[kc] = *reinterpret_cast<const half8*>(&sm.ts.hi[g * 16 + row16][kc * 32 + quad * 8]);
    al[kc] = *reinterpret_cast<const half8*>(&sm.ts.lo[g * 16 + row16][kc * 32 + quad * 8]);
  }
  __syncthreads();

  if (z < 2) {
    f16* outp = z ? kp : qp;
#pragma unroll
    for (int ct8 = 0; ct8 < 8; ++ct8) {
      int ct = h * 8 + ct8;
      f32x4 acc = {0.f, 0.f, 0.f, 0.f};
      const f16* bh = WT + ((size_t)ct * 8) * 512 + lane * 8;
#pragma unroll
      for (int kc = 0; kc < 8; ++kc) {
        half8 b = ldg8(bh + kc * 512);
        acc = __builtin_amdgcn_mfma_f32_16x16x32_f16(ah[kc], b, acc, 0, 0, 0);
        acc = __builtin_amdgcn_mfma_f32_16x16x32_f16(al[kc], b, acc, 0, 0, 0);
      }
      int co = ct * 16 + row16;
      float bb = bias[co];
#pragma unroll
      for (int r = 0; r < 4; ++r)
        sm.ex[g][quad * 4 + r][co] = (f16)(acc[r] + bb);
    }
    const f16* exr = &sm.ex[g][row16][0];
    size_t fb = ((size_t)bl * 64 + (n0 >> 4) + g) * 8;
#pragma unroll
    for (int k = 0; k < 4; ++k) {
      int kc = h * 4 + k;
      half8 hv = *reinterpret_cast<const half8*>(exr + kc * 32 + quad * 8);
      *reinterpret_cast<half8*>(outp + (fb + kc) * 512 + lane * 8) = hv;
    }
  } else {
#pragma unroll
    for (int ct8 = 0; ct8 < 8; ++ct8) {
      int ct = h * 8 + ct8;
      f32x4 acc = {0.f, 0.f, 0.f, 0.f};
      const f16* bh = WT + ((size_t)ct * 8) * 512 + lane * 8;
#pragma unroll
      for (int kc = 0; kc < 8; ++kc) {
        half8 b = ldg8(bh + kc * 512);
        acc = __builtin_amdgcn_mfma_f32_16x16x32_f16(ah[kc], b, acc, 0, 0, 0);
        acc = __builtin_amdgcn_mfma_f32_16x16x32_f16(al[kc], b, acc, 0, 0, 0);
      }
      int co = ct * 16 + row16;
      float bb = bias[co];
#pragma unroll
      for (int r = 0; r < 4; ++r)
        sm.exv[co][g * 16 + quad * 4 + r] = (f16)(acc[r] + bb);
    }
    __syncthreads();
    size_t vb = ((size_t)bl * 32 + blockIdx.y) * 16;
#pragma unroll
    for (int f = 0; f < 4; ++f) {
      int ct = wave * 4 + f;
      half8 o = *reinterpret_cast<const half8*>(&sm.exv[ct * 16 + row16][quad * 8]);
      *reinterpret_cast<half8*>(vp + (vb + ct) * 512 + lane * 8) = o;
    }
  }
}

// ---------------- fused flash attention + MLP(SiLU) + LayerNorm ----------------
// i-SPLIT version: grid (nb, 64). block 256 = 4 waves, ALL owning the SAME 16-row j-tile.
// Wave w sweeps i in [w*256, w*256+256) (2 iterations of 128 i), then the 4 partial online-
// softmax states (m, l, O) are combined: m/l via small LDS exchange, O via f32 LDS atomicAdd
// into a buffer aliased over the (now dead) P region. MLP + LN are split 4-ways across waves
// (4 output ct each), LN row-stats via an LDS partial exchange.
// This turns 1024 waves (1 wave/SIMD, 11% occupancy) into 4096 waves (3-4 blocks/CU).
struct AttnSmem {
  union {
    f16 P[4][4][16][40];     // per-wave P round-trip buffers (main loop)     20.0 KB
    float Oacc[16][260];     // cross-wave f32 O accumulator (epilogue)       16.3 KB
  } u;
  f16 ex[2][16][264];        // [0]: normalized att, [1]: MLP hidden h        16.5 KB
  float ml[4][2][16];        // per-wave {m, l} per j-row
  float lnbuf[4][2][16];     // per-wave LN partial {sum, ssq} per j-row
  float invL[16];            // 1/denominator per j-row
};

__global__ void __launch_bounds__(256) k_attn_mlp(
    const f16* __restrict__ qp, const f16* __restrict__ kp, const f16* __restrict__ vp,
    const f16* __restrict__ w1p, const float* __restrict__ b1,
    const f16* __restrict__ w2p, const float* __restrict__ b2,
    const float* __restrict__ gamma, const float* __restrict__ beta,
    float* __restrict__ out, int b_base) {
  __shared__ AttnSmem sm;
  int bl = blockIdx.x, bg = b_base + bl;
  int jt = blockIdx.y;            // 0..63, one 16-row j-tile per block
  int j0 = jt * 16;
  int tid = threadIdx.x, wave = tid >> 6, lane = tid & 63;
  int row16 = lane & 15, quad = lane >> 4;

  // A-frags: k rows of this block's j-tile (same for all 4 waves; L2-resident)
  const f16* kbase = kp + (size_t)bl * NN * CC;
  half8 kf[8];
#pragma unroll
  for (int kc = 0; kc < 8; ++kc)
    kf[kc] = ldg8(kbase + ((size_t)jt * 8 + kc) * 512 + lane * 8);

  const f16* qbase = qp + (size_t)bl * NN * CC;
  const f16* vbase = vp + (size_t)bl * CC * NN;

  f32x4 O[16];
#pragma unroll
  for (int ct = 0; ct < 16; ++ct) O[ct] = {0.f, 0.f, 0.f, 0.f};
  float m_run[4], l_lane[4];
#pragma unroll
  for (int r = 0; r < 4; ++r) { m_run[r] = -1e30f; l_lane[r] = 0.f; }

  // ---- main loop: this wave's 2 iterations of 128 i ----
#pragma unroll
  for (int ii = 0; ii < 2; ++ii) {
    int it = wave * 2 + ii;
    // scores S[16 j][128 i]: 8 frags, 8 parallel MFMA chains
    f32x4 s[8];
#pragma unroll
    for (int f = 0; f < 8; ++f) s[f] = {0.f, 0.f, 0.f, 0.f};
#pragma unroll
    for (int kc = 0; kc < 8; ++kc) {
#pragma unroll
      for (int f = 0; f < 8; ++f) {
        half8 b = ldg8(qbase + ((size_t)(it * 8 + f) * 8 + kc) * 512 + lane * 8);
        s[f] = __builtin_amdgcn_mfma_f32_16x16x32_f16(kf[kc], b, s[f], 0, 0, 0);
      }
    }

    // softmax per j-row over 128 i (max-reduce in-loop; l accumulated lazily per-lane)
    float alpha[4];
#pragma unroll
    for (int r = 0; r < 4; ++r) {
      float mx = s[0][r];
#pragma unroll
      for (int f = 1; f < 8; ++f) mx = fmaxf(mx, s[f][r]);
#pragma unroll
      for (int off = 1; off < 16; off <<= 1) mx = fmaxf(mx, __shfl_xor(mx, off, 64));
      float mnew = fmaxf(m_run[r], mx);
      alpha[r] = __expf(m_run[r] - mnew);
      m_run[r] = mnew;
      float ps = 0.f;
#pragma unroll
      for (int f = 0; f < 8; ++f) {
        float pv = __expf(s[f][r] - mnew);
        ps += pv;
        sm.u.P[wave][f >> 1][quad * 4 + r][(f & 1) * 16 + row16] = (f16)pv;
      }
      l_lane[r] = l_lane[r] * alpha[r] + ps;
    }
#pragma unroll
    for (int ct = 0; ct < 16; ++ct)
#pragma unroll
      for (int r = 0; r < 4; ++r) O[ct][r] *= alpha[r];

    // PV: 4 chunks of 32 i; P same-wave LDS round-trip, packed vT frags
#pragma unroll
    for (int c4 = 0; c4 < 4; ++c4) {
      half8 pf = *reinterpret_cast<const half8*>(&sm.u.P[wave][c4][row16][quad * 8]);
      size_t vfb = ((size_t)(it * 4 + c4) * 16) * 512;
#pragma unroll
      for (int ct = 0; ct < 16; ++ct) {
        half8 vf = ldg8(vbase + vfb + (size_t)ct * 512 + lane * 8);
        O[ct] = __builtin_amdgcn_mfma_f32_16x16x32_f16(pf, vf, O[ct], 0, 0, 0);
      }
    }
  }

  // ---- cross-wave combine of (m, l, O) ----
  // in-wave l reduction over the 16-lane i-groups
#pragma unroll
  for (int r = 0; r < 4; ++r) {
#pragma unroll
    for (int off = 1; off < 16; off <<= 1) l_lane[r] += __shfl_xor(l_lane[r], off, 64);
  }
  if (row16 == 0) {
#pragma unroll
    for (int r = 0; r < 4; ++r) {
      sm.ml[wave][0][quad * 4 + r] = m_run[r];
      sm.ml[wave][1][quad * 4 + r] = l_lane[r];
    }
  }
  __syncthreads();   // ml visible; all waves done with P region

  // zero the O accumulator (aliases P, which is now dead)
  {
    float* oflat = &sm.u.Oacc[0][0];
    for (int t = tid; t < 16 * 260; t += 256) oflat[t] = 0.f;
  }

  // global M, L per j-row; this wave's rescale factor
  float alphaW[4];
#pragma unroll
  for (int r = 0; r < 4; ++r) {
    int j = quad * 4 + r;
    float M = sm.ml[0][0][j];
#pragma unroll
    for (int w = 1; w < 4; ++w) M = fmaxf(M, sm.ml[w][0][j]);
    float L = 0.f;
#pragma unroll
    for (int w = 0; w < 4; ++w) L += sm.ml[w][1][j] * __expf(sm.ml[w][0][j] - M);
    alphaW[r] = __expf(m_run[r] - M);
    if (row16 == 0) sm.invL[j] = 1.f / L;   // identical value from every wave: benign race
  }
  __syncthreads();   // zeros visible before atomics

#pragma unroll
  for (int ct = 0; ct < 16; ++ct)
#pragma unroll
    for (int r = 0; r < 4; ++r)
      atomicAdd(&sm.u.Oacc[quad * 4 + r][ct * 16 + row16], O[ct][r] * alphaW[r]);
  __syncthreads();   // combined O visible

  // normalize + convert to f16 att (cooperative, coalesced over LDS banks)
  for (int t = tid; t < 4096; t += 256) {
    int j = t >> 8, c = t & 255;
    sm.ex[0][j][c] = (f16)(sm.u.Oacc[j][c] * sm.invL[j]);
  }
  __syncthreads();   // att tile ready

  // ---- MLP + LN, split 4-ways across waves (4 ct each) ----
  half8 af[8];
#pragma unroll
  for (int kc = 0; kc < 8; ++kc)
    af[kc] = *reinterpret_cast<const half8*>(&sm.ex[0][row16][kc * 32 + quad * 8]);

  // GEMM1: h = silu(att @ w1 + b1) -> ex[1]
#pragma unroll
  for (int q = 0; q < 4; ++q) {
    int ct = wave * 4 + q;
    f32x4 acc = {0.f, 0.f, 0.f, 0.f};
    const f16* brow = w1p + ((size_t)ct * 8) * 512 + lane * 8;
#pragma unroll
    for (int kc = 0; kc < 8; ++kc)
      acc = __builtin_amdgcn_mfma_f32_16x16x32_f16(af[kc], ldg8(brow + kc * 512), acc, 0, 0, 0);
    int co = ct * 16 + row16;
    float bb = b1[co];
#pragma unroll
    for (int r = 0; r < 4; ++r) {
      float xg = acc[r] + bb;
      float hh = xg / (1.f + __expf(-xg));  // SiLU
      sm.ex[1][quad * 4 + r][co] = (f16)hh;
    }
  }
  __syncthreads();   // full h tile ready

  half8 hf[8];
#pragma unroll
  for (int kc = 0; kc < 8; ++kc)
    hf[kc] = *reinterpret_cast<const half8*>(&sm.ex[1][row16][kc * 32 + quad * 8]);

  f32x4 acc2[4];
#pragma unroll
  for (int q = 0; q < 4; ++q) {
    int ct = wave * 4 + q;
    f32x4 acc = {0.f, 0.f, 0.f, 0.f};
    const f16* brow = w2p + ((size_t)ct * 8) * 512 + lane * 8;
#pragma unroll
    for (int kc = 0; kc < 8; ++kc)
      acc = __builtin_amdgcn_mfma_f32_16x16x32_f16(hf[kc], ldg8(brow + kc * 512), acc, 0, 0, 0);
    float bb = b2[ct * 16 + row16];
#pragma unroll
    for (int r = 0; r < 4; ++r) acc[r] += bb;
    acc2[q] = acc;
  }

  // LayerNorm over C: per-wave partials (64 channels each) -> LDS exchange -> finalize
  float sum[4] = {0.f, 0.f, 0.f, 0.f}, ssq[4] = {0.f, 0.f, 0.f, 0.f};
#pragma unroll
  for (int q = 0; q < 4; ++q)
#pragma unroll
    for (int r = 0; r < 4; ++r) { float xv = acc2[q][r]; sum[r] += xv; ssq[r] += xv * xv; }
#pragma unroll
  for (int r = 0; r < 4; ++r) {
#pragma unroll
    for (int off = 1; off < 16; off <<= 1) {
      sum[r] += __shfl_xor(sum[r], off, 64);
      ssq[r] += __shfl_xor(ssq[r], off, 64);
    }
  }
  if (row16 == 0) {
#pragma unroll
    for (int r = 0; r < 4; ++r) {
      sm.lnbuf[wave][0][quad * 4 + r] = sum[r];
      sm.lnbuf[wave][1][quad * 4 + r] = ssq[r];
    }
  }
  __syncthreads();   // LN partials visible

  float mean[4], rstd[4];
#pragma unroll
  for (int r = 0; r < 4; ++r) {
    int j = quad * 4 + r;
    float s = 0.f, sq = 0.f;
#pragma unroll
    for (int w = 0; w < 4; ++w) { s += sm.lnbuf[w][0][j]; sq += sm.lnbuf[w][1][j]; }
    mean[r] = s * (1.f / 256.f);
    float var = sq * (1.f / 256.f) - mean[r] * mean[r];
    rstd[r] = rsqrtf(var + 1e-5f);
  }

  // coalesced stores: out[bg][col][j0 + quad*4 .. +3] = float4 (this wave's 64 cols)
#pragma unroll
  for (int q = 0; q < 4; ++q) {
    int col = (wave * 4 + q) * 16 + row16;
    float g = gamma[col], be = beta[col];
    f32x4 v;
#pragma unroll
    for (int r = 0; r < 4; ++r) v[r] = (acc2[q][r] - mean[r]) * rstd[r] * g + be;
    *reinterpret_cast<f32x4*>(out + (size_t)(bg * CC + col) * NN + j0 + quad * 4) = v;
  }
}

extern "C" void kernel_launch(void* const* d_in, const int* in_sizes, int n_in,
                              void* d_out, int out_size, void* d_ws, size_t ws_size,
                              hipStream_t stream) {
  (void)in_sizes; (void)n_in; (void)out_size;
  const float* x     = (const float*)d_in[0];
  const float* wq    = (const float*)d_in[1];
  const float* bq    = (const float*)d_in[2];
  const float* wk    = (const float*)d_in[3];
  const float* bk    = (const float*)d_in[4];
  const float* wv    = (const float*)d_in[5];
  const float* bv    = (const float*)d_in[6];
  const float* w1    = (const float*)d_in[7];
  const float* b1    = (const float*)d_in[8];
  const float* w2    = (const float*)d_in[9];
  const float* b2    = (const float*)d_in[10];
  const float* gamma = (const float*)d_in[11];
  const float* beta  = (const float*)d_in[12];
  float* out = (float*)d_out;

  const size_t WE = 65536;
  const size_t SB = (size_t)NN * CC;
  f16* base = (f16*)d_ws;
  f16* wqp = base + 0 * WE;
  f16* wkp = base + 1 * WE;
  f16* wvp = base + 2 * WE;
  f16* w1p = base + 3 * WE;
  f16* w2p = base + 4 * WE;

  size_t wbytes = 5 * WE * sizeof(f16);
  size_t perb   = 3 * SB * sizeof(f16);
  int nb = (ws_size > wbytes) ? (int)((ws_size - wbytes) / perb) : 1;
  if (nb < 1) nb = 1;
  if (nb > BB) nb = BB;

  f16* qb  = base + 5 * WE;
  f16* kb  = qb + (size_t)nb * SB;
  f16* vTb = kb + (size_t)nb * SB;

  WP5 p;
  p.s[0] = wq; p.s[1] = wk; p.s[2] = wv; p.s[3] = w1; p.s[4] = w2;
  p.d[0] = wqp; p.d[1] = wkp; p.d[2] = wvp; p.d[3] = w1p; p.d[4] = w2p;
  k_packW<<<dim3(16, 5), 256, 0, stream>>>(p);

  for (int b0 = 0; b0 < BB; b0 += nb) {
    int cb = (b0 + nb <= BB) ? nb : (BB - b0);
    k_qkv<<<dim3(cb, 32, 3), 256, 0, stream>>>(x, wqp, wkp, wvp, bq, bk, bv, qb, kb, vTb, b0);
    k_attn_mlp<<<dim3(cb, 64), 256, 0, stream>>>(qb, kb, vTb, w1p, b1, w2p, b2,
                                                 gamma, beta, out, b0);
  }
}

// Round 2
// 203.009 us; speedup vs baseline: 1.4058x; 1.4058x over previous
//
#include <hip/hip_runtime.h>

#define BB 16
#define CC 256
#define NN 1024

typedef _Float16 f16;
typedef __attribute__((ext_vector_type(8))) _Float16 half8;   // MFMA A/B frag (4 VGPRs)
typedef __attribute__((ext_vector_type(4))) float f32x4;      // MFMA C/D frag

__device__ __forceinline__ half8 ldg8(const f16* p) {
  return *reinterpret_cast<const half8*>(p);
}

// async global->LDS, 16B per lane; lds base must be wave-uniform (HW adds lane*16)
__device__ __forceinline__ void gll16(const f16* g, f16* l) {
  __builtin_amdgcn_global_load_lds((const __attribute__((address_space(1))) void*)g,
                                   (__attribute__((address_space(3))) void*)l, 16, 0, 0);
}

#define VMCNT(n) asm volatile("s_waitcnt vmcnt(" #n ")" ::: "memory")
#define BAR() __builtin_amdgcn_s_barrier()

// stage one contiguous 64 KB chunk (32768 f16) with 256 threads: 16 issues/thread.
// per issue k: wave w's 64 lanes write LDS [k*2048 + w*512 .. +512) (f16 units), linear both sides.
__device__ __forceinline__ void stage64k(const f16* __restrict__ g, f16* l, int wave, int lane) {
#pragma unroll
  for (int k = 0; k < 16; ++k) {
    int ob = k * 2048 + wave * 512;      // wave-uniform f16 offset
    gll16(g + ob + lane * 8, l + ob);
  }
}

// ---------------- weight pack: W fp32 [ci][co] -> frag-packed f16 wp[(ct*8+kc)*512 + lane*8] ----
struct WP5 {
  const float* s[5];
  f16* d[5];
};

__global__ void __launch_bounds__(256) k_packW(WP5 p) {
  __shared__ float ws[256][17];
  int m = blockIdx.y, ct = blockIdx.x;
  const float* W = p.s[m];
  f16* wp = p.d[m];
  int tid = threadIdx.x;
  int col = tid & 15, cig = tid >> 4;
#pragma unroll
  for (int pg = 0; pg < 16; ++pg) {
    int ci = pg * 16 + cig;
    ws[ci][col] = W[(size_t)ci * 256 + ct * 16 + col];
  }
  __syncthreads();
  int lane = tid & 63, wave = tid >> 6;
  int row16 = lane & 15, quad = lane >> 4;
#pragma unroll
  for (int kk = 0; kk < 2; ++kk) {
    int kc = wave * 2 + kk;
    half8 o;
#pragma unroll
    for (int j = 0; j < 8; ++j) o[j] = (f16)ws[kc * 32 + quad * 8 + j][row16];
    *reinterpret_cast<half8*>(wp + ((size_t)ct * 8 + kc) * 512 + lane * 8) = o;
  }
}

// ---------------- QKV: x fp32 [bg][c][n] -> frag-packed q,k,vT (unchanged) ----------------
struct QkvSmem {
  union {
    struct { f16 hi[32][264]; f16 lo[32][264]; } ts;
    f16 ex[2][16][264];
    f16 exv[256][40];
  };
};

__global__ void __launch_bounds__(256) k_qkv(const float* __restrict__ x,
    const f16* __restrict__ wqp, const f16* __restrict__ wkp, const f16* __restrict__ wvp,
    const float* __restrict__ bq, const float* __restrict__ bk, const float* __restrict__ bv,
    f16* __restrict__ qp, f16* __restrict__ kp, f16* __restrict__ vp, int b_base) {
  __shared__ QkvSmem sm;
  int z = blockIdx.z;
  const f16* WT     = (z == 0) ? wqp : (z == 1) ? wkp : wvp;
  const float* bias = (z == 0) ? bq  : (z == 1) ? bk  : bv;
  int bl = blockIdx.x, bg = b_base + bl, n0 = blockIdx.y * 32;
  int tid = threadIdx.x, wave = tid >> 6, lane = tid & 63;
  int row16 = lane & 15, quad = lane >> 4;
  int g = wave >> 1, h = wave & 1;

#pragma unroll
  for (int e = tid; e < 2048; e += 256) {
    int c = e >> 3, n4 = (e & 7) << 2;
    float4 u = *reinterpret_cast<const float4*>(x + (size_t)(bg * CC + c) * NN + n0 + n4);
    float uv[4] = {u.x, u.y, u.z, u.w};
#pragma unroll
    for (int i = 0; i < 4; ++i) {
      f16 hh = (f16)uv[i];
      sm.ts.hi[n4 + i][c] = hh;
      sm.ts.lo[n4 + i][c] = (f16)(uv[i] - (float)hh);
    }
  }
  __syncthreads();

  half8 ah[8], al[8];
#pragma unroll
  for (int kc = 0; kc < 8; ++kc) {
    ah[kc] = *reinterpret_cast<const half8*>(&sm.ts.hi[g * 16 + row16][kc * 32 + quad * 8]);
    al[kc] = *reinterpret_cast<const half8*>(&sm.ts.lo[g * 16 + row16][kc * 32 + quad * 8]);
  }
  __syncthreads();

  if (z < 2) {
    f16* outp = z ? kp : qp;
#pragma unroll
    for (int ct8 = 0; ct8 < 8; ++ct8) {
      int ct = h * 8 + ct8;
      f32x4 acc = {0.f, 0.f, 0.f, 0.f};
      const f16* bh = WT + ((size_t)ct * 8) * 512 + lane * 8;
#pragma unroll
      for (int kc = 0; kc < 8; ++kc) {
        half8 b = ldg8(bh + kc * 512);
        acc = __builtin_amdgcn_mfma_f32_16x16x32_f16(ah[kc], b, acc, 0, 0, 0);
        acc = __builtin_amdgcn_mfma_f32_16x16x32_f16(al[kc], b, acc, 0, 0, 0);
      }
      int co = ct * 16 + row16;
      float bb = bias[co];
#pragma unroll
      for (int r = 0; r < 4; ++r)
        sm.ex[g][quad * 4 + r][co] = (f16)(acc[r] + bb);
    }
    const f16* exr = &sm.ex[g][row16][0];
    size_t fb = ((size_t)bl * 64 + (n0 >> 4) + g) * 8;
#pragma unroll
    for (int k = 0; k < 4; ++k) {
      int kc = h * 4 + k;
      half8 hv = *reinterpret_cast<const half8*>(exr + kc * 32 + quad * 8);
      *reinterpret_cast<half8*>(outp + (fb + kc) * 512 + lane * 8) = hv;
    }
  } else {
#pragma unroll
    for (int ct8 = 0; ct8 < 8; ++ct8) {
      int ct = h * 8 + ct8;
      f32x4 acc = {0.f, 0.f, 0.f, 0.f};
      const f16* bh = WT + ((size_t)ct * 8) * 512 + lane * 8;
#pragma unroll
      for (int kc = 0; kc < 8; ++kc) {
        half8 b = ldg8(bh + kc * 512);
        acc = __builtin_amdgcn_mfma_f32_16x16x32_f16(ah[kc], b, acc, 0, 0, 0);
        acc = __builtin_amdgcn_mfma_f32_16x16x32_f16(al[kc], b, acc, 0, 0, 0);
      }
      int co = ct * 16 + row16;
      float bb = bias[co];
#pragma unroll
      for (int r = 0; r < 4; ++r)
        sm.exv[co][g * 16 + quad * 4 + r] = (f16)(acc[r] + bb);
    }
    __syncthreads();
    size_t vb = ((size_t)bl * 32 + blockIdx.y) * 16;
#pragma unroll
    for (int f = 0; f < 4; ++f) {
      int ct = wave * 4 + f;
      half8 o = *reinterpret_cast<const half8*>(&sm.exv[ct * 16 + row16][quad * 8]);
      *reinterpret_cast<half8*>(vp + (vb + ct) * 512 + lane * 8) = o;
    }
  }
}

// ---------------- fused flash attention + MLP(SiLU) + LayerNorm ----------------
// LDS-PIPELINED version. grid (nb, 16). block 256 = 4 waves, each owning one 16-row j-tile
// (zero cross-wave combine). All 4 waves share the SAME i-sweep, so the block cooperatively
// stages the 128-i Q-chunk (64 KB) and V-chunk (64 KB) into LDS with async global_load_lds,
// phase-offset prefetch: next-Q issued after QK (hides under softmax+PV), next-V issued after
// PV (hides under next QK). Counted vmcnt(16) — loads stay in flight across raw s_barriers.
// This replaces 128 VGPR-starved per-wave global ldg8 per iteration (the measured latency
// stall: MfmaUtil 5%, occupancy-locked 1 block/CU) with conflict-free ds_read_b128.
struct AttnSmem {
  union {
    struct {
      f16 QB[128 * 256];   // 64 KB: packed q frags, current 128-i chunk (contiguous copy)
      f16 VB[128 * 256];   // 64 KB: packed vT frags, current 128-i chunk
    } s;
    f16 ex[4][16][264];    // epilogue per-wave exchange (att, h)   66 KB (aliases QB+VB head)
  } u;
  f16 P[4][4][16][40];     // per-wave P round-trip (C->A layout)   20 KB
};

__global__ void __launch_bounds__(256) k_attn_mlp(
    const f16* __restrict__ qp, const f16* __restrict__ kp, const f16* __restrict__ vp,
    const f16* __restrict__ w1p, const float* __restrict__ b1,
    const f16* __restrict__ w2p, const float* __restrict__ b2,
    const float* __restrict__ gamma, const float* __restrict__ beta,
    float* __restrict__ out, int b_base) {
  __shared__ AttnSmem sm;
  int bl = blockIdx.x, bg = b_base + bl;
  int j0 = blockIdx.y * 64;
  int tid = threadIdx.x, wave = tid >> 6, lane = tid & 63;
  int row16 = lane & 15, quad = lane >> 4;
  int jw = j0 + wave * 16;

  // A-frags: k rows of this wave's j-tile (8 loads, issued first so prologue vmcnt covers them)
  const f16* kbase = kp + (size_t)bl * NN * CC;
  int jt = (j0 >> 4) + wave;
  half8 kf[8];
#pragma unroll
  for (int kc = 0; kc < 8; ++kc)
    kf[kc] = ldg8(kbase + ((size_t)jt * 8 + kc) * 512 + lane * 8);

  const f16* qbase = qp + (size_t)bl * NN * CC;
  const f16* vbase = vp + (size_t)bl * CC * NN;

  // prologue: stage chunk 0 of Q and V; wait Q (and kf) landed, leave V in flight
  stage64k(qbase, sm.u.s.QB, wave, lane);
  stage64k(vbase, sm.u.s.VB, wave, lane);
  VMCNT(16);   // 8 kf + 16 Q + 16 V outstanding -> wait to 16: kf + Q done, V in flight
  BAR();

  f32x4 O[16];
#pragma unroll
  for (int ct = 0; ct < 16; ++ct) O[ct] = {0.f, 0.f, 0.f, 0.f};
  float m_run[4], l_lane[4];
#pragma unroll
  for (int r = 0; r < 4; ++r) { m_run[r] = -1e30f; l_lane[r] = 0.f; }

  for (int it = 0; it < 8; ++it) {
    // ---- QK: scores S[16 j][128 i] from LDS (conflict-free b128), 8 parallel chains ----
    f32x4 s[8];
#pragma unroll
    for (int f = 0; f < 8; ++f) s[f] = {0.f, 0.f, 0.f, 0.f};
#pragma unroll
    for (int kc = 0; kc < 8; ++kc) {
#pragma unroll
      for (int f = 0; f < 8; ++f) {
        half8 b = *reinterpret_cast<const half8*>(&sm.u.s.QB[(f * 8 + kc) * 512 + lane * 8]);
        s[f] = __builtin_amdgcn_mfma_f32_16x16x32_f16(kf[kc], b, s[f], 0, 0, 0);
      }
    }
    BAR();                                                    // (a) all waves done reading QB
    stage64k(qbase + (size_t)((it + 1) & 7) * 32768, sm.u.s.QB, wave, lane);  // next Q in flight

    // ---- softmax per j-row over 128 i (overlaps Q staging) ----
    float alpha[4];
#pragma unroll
    for (int r = 0; r < 4; ++r) {
      float mx = s[0][r];
#pragma unroll
      for (int f = 1; f < 8; ++f) mx = fmaxf(mx, s[f][r]);
#pragma unroll
      for (int off = 1; off < 16; off <<= 1) mx = fmaxf(mx, __shfl_xor(mx, off, 64));
      float mnew = fmaxf(m_run[r], mx);
      alpha[r] = __expf(m_run[r] - mnew);
      m_run[r] = mnew;
      float ps = 0.f;
#pragma unroll
      for (int f = 0; f < 8; ++f) {
        float pv = __expf(s[f][r] - mnew);
        ps += pv;
        sm.P[wave][f >> 1][quad * 4 + r][(f & 1) * 16 + row16] = (f16)pv;
      }
      l_lane[r] = l_lane[r] * alpha[r] + ps;
    }
#pragma unroll
    for (int ct = 0; ct < 16; ++ct)
#pragma unroll
      for (int r = 0; r < 4; ++r) O[ct][r] *= alpha[r];

    VMCNT(16);   // V(it) landed (only next-Q's 16 may remain in flight)
    BAR();       // (b) all waves' V(it) visible

    // ---- PV: 4 chunks of 32 i; P same-wave LDS round-trip, vT frags from LDS ----
#pragma unroll
    for (int c4 = 0; c4 < 4; ++c4) {
      half8 pf = *reinterpret_cast<const half8*>(&sm.P[wave][c4][row16][quad * 8]);
#pragma unroll
      for (int ct = 0; ct < 16; ++ct) {
        half8 vf = *reinterpret_cast<const half8*>(&sm.u.s.VB[(c4 * 16 + ct) * 512 + lane * 8]);
        O[ct] = __builtin_amdgcn_mfma_f32_16x16x32_f16(pf, vf, O[ct], 0, 0, 0);
      }
    }
    BAR();                                                    // (c) all waves done reading VB
    stage64k(vbase + (size_t)((it + 1) & 7) * 32768, sm.u.s.VB, wave, lane);  // next V in flight
    VMCNT(16);   // Q(it+1) landed (only next-V's 16 remain)
    BAR();       // (d) all waves' Q(it+1) visible
  }
  VMCNT(0);      // drain the wrap-around stages before aliasing ex over QB/VB
  BAR();

  // final l reduction (once) and normalization
  float inv[4];
#pragma unroll
  for (int r = 0; r < 4; ++r) {
    float l = l_lane[r];
#pragma unroll
    for (int off = 1; off < 16; off <<= 1) l += __shfl_xor(l, off, 64);
    inv[r] = 1.f / l;
  }

  // ---- phase B: MLP + LN on this wave's 16x256 att tile (per-wave LDS only) ----
#pragma unroll
  for (int ct = 0; ct < 16; ++ct)
#pragma unroll
    for (int r = 0; r < 4; ++r)
      sm.u.ex[wave][quad * 4 + r][ct * 16 + row16] = (f16)(O[ct][r] * inv[r]);

  half8 af[8];
#pragma unroll
  for (int kc = 0; kc < 8; ++kc)
    af[kc] = *reinterpret_cast<const half8*>(&sm.u.ex[wave][row16][kc * 32 + quad * 8]);

  // GEMM1: h = silu(att @ w1 + b1) -> ex (own-wave rows); packed weight frags
#pragma unroll
  for (int ct = 0; ct < 16; ++ct) {
    f32x4 acc = {0.f, 0.f, 0.f, 0.f};
    const f16* brow = w1p + ((size_t)ct * 8) * 512 + lane * 8;
#pragma unroll
    for (int kc = 0; kc < 8; ++kc)
      acc = __builtin_amdgcn_mfma_f32_16x16x32_f16(af[kc], ldg8(brow + kc * 512), acc, 0, 0, 0);
    int co = ct * 16 + row16;
    float bb = b1[co];
#pragma unroll
    for (int r = 0; r < 4; ++r) {
      float xg = acc[r] + bb;
      float hh = xg / (1.f + __expf(-xg));  // SiLU
      sm.u.ex[wave][quad * 4 + r][co] = (f16)hh;
    }
  }

  half8 hf[8];
#pragma unroll
  for (int kc = 0; kc < 8; ++kc)
    hf[kc] = *reinterpret_cast<const half8*>(&sm.u.ex[wave][row16][kc * 32 + quad * 8]);

  f32x4 acc2[16];
#pragma unroll
  for (int ct = 0; ct < 16; ++ct) {
    f32x4 acc = {0.f, 0.f, 0.f, 0.f};
    const f16* brow = w2p + ((size_t)ct * 8) * 512 + lane * 8;
#pragma unroll
    for (int kc = 0; kc < 8; ++kc)
      acc = __builtin_amdgcn_mfma_f32_16x16x32_f16(hf[kc], ldg8(brow + kc * 512), acc, 0, 0, 0);
    float bb = b2[ct * 16 + row16];
#pragma unroll
    for (int r = 0; r < 4; ++r) acc[r] += bb;
    acc2[ct] = acc;
  }

  // LayerNorm over C (per-row stats via 16-lane butterfly)
  float sum[4] = {0.f, 0.f, 0.f, 0.f}, ssq[4] = {0.f, 0.f, 0.f, 0.f};
#pragma unroll
  for (int ct = 0; ct < 16; ++ct)
#pragma unroll
    for (int r = 0; r < 4; ++r) { float xv = acc2[ct][r]; sum[r] += xv; ssq[r] += xv * xv; }
  float mean[4], rstd[4];
#pragma unroll
  for (int r = 0; r < 4; ++r) {
#pragma unroll
    for (int off = 1; off < 16; off <<= 1) {
      sum[r] += __shfl_xor(sum[r], off, 64);
      ssq[r] += __shfl_xor(ssq[r], off, 64);
    }
    mean[r] = sum[r] * (1.f / 256.f);
    float var = ssq[r] * (1.f / 256.f) - mean[r] * mean[r];
    rstd[r] = rsqrtf(var + 1e-5f);
  }

  // direct coalesced stores: out[bg][col][jw + quad*4 .. +3] = float4
#pragma unroll
  for (int ct = 0; ct < 16; ++ct) {
    int col = ct * 16 + row16;
    float g = gamma[col], be = beta[col];
    f32x4 v;
#pragma unroll
    for (int r = 0; r < 4; ++r) v[r] = (acc2[ct][r] - mean[r]) * rstd[r] * g + be;
    *reinterpret_cast<f32x4*>(out + (size_t)(bg * CC + col) * NN + jw + quad * 4) = v;
  }
}

extern "C" void kernel_launch(void* const* d_in, const int* in_sizes, int n_in,
                              void* d_out, int out_size, void* d_ws, size_t ws_size,
                              hipStream_t stream) {
  (void)in_sizes; (void)n_in; (void)out_size;
  const float* x     = (const float*)d_in[0];
  const float* wq    = (const float*)d_in[1];
  const float* bq    = (const float*)d_in[2];
  const float* wk    = (const float*)d_in[3];
  const float* bk    = (const float*)d_in[4];
  const float* wv    = (const float*)d_in[5];
  const float* bv    = (const float*)d_in[6];
  const float* w1    = (const float*)d_in[7];
  const float* b1    = (const float*)d_in[8];
  const float* w2    = (const float*)d_in[9];
  const float* b2    = (const float*)d_in[10];
  const float* gamma = (const float*)d_in[11];
  const float* beta  = (const float*)d_in[12];
  float* out = (float*)d_out;

  const size_t WE = 65536;
  const size_t SB = (size_t)NN * CC;
  f16* base = (f16*)d_ws;
  f16* wqp = base + 0 * WE;
  f16* wkp = base + 1 * WE;
  f16* wvp = base + 2 * WE;
  f16* w1p = base + 3 * WE;
  f16* w2p = base + 4 * WE;

  size_t wbytes = 5 * WE * sizeof(f16);
  size_t perb   = 3 * SB * sizeof(f16);
  int nb = (ws_size > wbytes) ? (int)((ws_size - wbytes) / perb) : 1;
  if (nb < 1) nb = 1;
  if (nb > BB) nb = BB;

  f16* qb  = base + 5 * WE;
  f16* kb  = qb + (size_t)nb * SB;
  f16* vTb = kb + (size_t)nb * SB;

  WP5 p;
  p.s[0] = wq; p.s[1] = wk; p.s[2] = wv; p.s[3] = w1; p.s[4] = w2;
  p.d[0] = wqp; p.d[1] = wkp; p.d[2] = wvp; p.d[3] = w1p; p.d[4] = w2p;
  k_packW<<<dim3(16, 5), 256, 0, stream>>>(p);

  for (int b0 = 0; b0 < BB; b0 += nb) {
    int cb = (b0 + nb <= BB) ? nb : (BB - b0);
    k_qkv<<<dim3(cb, 32, 3), 256, 0, stream>>>(x, wqp, wkp, wvp, bq, bk, bv, qb, kb, vTb, b0);
    k_attn_mlp<<<dim3(cb, 16), 256, 0, stream>>>(qb, kb, vTb, w1p, b1, w2p, b2,
                                                 gamma, beta, out, b0);
  }
}

// Round 3
// 199.609 us; speedup vs baseline: 1.4298x; 1.0170x over previous
//
#include <hip/hip_runtime.h>

#define BB 16
#define CC 256
#define NN 1024

typedef _Float16 f16;
typedef __attribute__((ext_vector_type(8))) _Float16 half8;   // MFMA A/B frag (4 VGPRs)
typedef __attribute__((ext_vector_type(4))) float f32x4;      // MFMA C/D frag

__device__ __forceinline__ half8 ldg8(const f16* p) {
  return *reinterpret_cast<const half8*>(p);
}

// async global->LDS, 16B per lane; lds base must be wave-uniform (HW adds lane*16)
__device__ __forceinline__ void gll16(const f16* g, f16* l) {
  __builtin_amdgcn_global_load_lds((const __attribute__((address_space(1))) void*)g,
                                   (__attribute__((address_space(3))) void*)l, 16, 0, 0);
}

#define VMCNT(n) asm volatile("s_waitcnt vmcnt(" #n ")" ::: "memory")
#define BAR() __builtin_amdgcn_s_barrier()

// stage one contiguous 64 KB chunk (32768 f16) with 256 threads: 16 issues/thread.
__device__ __forceinline__ void stage64k(const f16* __restrict__ g, f16* l, int wave, int lane) {
#pragma unroll
  for (int k = 0; k < 16; ++k) {
    int ob = k * 2048 + wave * 512;      // wave-uniform f16 offset
    gll16(g + ob + lane * 8, l + ob);
  }
}

// ---------------- weight pack: W fp32 [ci][co] -> frag-packed f16 wp[(ct*8+kc)*512 + lane*8] ----
struct WP5 {
  const float* s[5];
  f16* d[5];
};

__global__ void __launch_bounds__(256) k_packW(WP5 p) {
  __shared__ float ws[256][17];
  int m = blockIdx.y, ct = blockIdx.x;
  const float* W = p.s[m];
  f16* wp = p.d[m];
  int tid = threadIdx.x;
  int col = tid & 15, cig = tid >> 4;
#pragma unroll
  for (int pg = 0; pg < 16; ++pg) {
    int ci = pg * 16 + cig;
    ws[ci][col] = W[(size_t)ci * 256 + ct * 16 + col];
  }
  __syncthreads();
  int lane = tid & 63, wave = tid >> 6;
  int row16 = lane & 15, quad = lane >> 4;
#pragma unroll
  for (int kk = 0; kk < 2; ++kk) {
    int kc = wave * 2 + kk;
    half8 o;
#pragma unroll
    for (int j = 0; j < 8; ++j) o[j] = (f16)ws[kc * 32 + quad * 8 + j][row16];
    *reinterpret_cast<half8*>(wp + ((size_t)ct * 8 + kc) * 512 + lane * 8) = o;
  }
}

// ---------------- QKV (z-MERGED): x fp32 [bg][c][n] -> frag-packed q,k,vT ----------------
// One block = one 32-i chunk of one batch, computing ALL of q, k, v from a single x
// load + hi/lo conversion (was 3x redundant across the old z-grid). A-frags stay in
// registers across the three projections. Each projection phase uses 4 output-tiles x
// separate hi/lo accumulators = 8 independent MFMA chains (dep distance 8 issues).
struct QkvSmem {
  union {
    struct { f16 hi[32][264]; f16 lo[32][264]; } ts;
    f16 ex[2][16][264];
    f16 exv[256][40];
  };
};

__global__ void __launch_bounds__(256) k_qkv(const float* __restrict__ x,
    const f16* __restrict__ wqp, const f16* __restrict__ wkp, const f16* __restrict__ wvp,
    const float* __restrict__ bq, const float* __restrict__ bk, const float* __restrict__ bv,
    f16* __restrict__ qp, f16* __restrict__ kp, f16* __restrict__ vp, int b_base) {
  __shared__ QkvSmem sm;
  int bl = blockIdx.x, bg = b_base + bl, n0 = blockIdx.y * 32;
  int tid = threadIdx.x, wave = tid >> 6, lane = tid & 63;
  int row16 = lane & 15, quad = lane >> 4;
  int g = wave >> 1, h = wave & 1;

  // ---- load x chunk once; split into hi/lo f16 halves, transposed into LDS ----
#pragma unroll
  for (int e = tid; e < 2048; e += 256) {
    int c = e >> 3, n4 = (e & 7) << 2;
    float4 u = *reinterpret_cast<const float4*>(x + (size_t)(bg * CC + c) * NN + n0 + n4);
    float uv[4] = {u.x, u.y, u.z, u.w};
#pragma unroll
    for (int i = 0; i < 4; ++i) {
      f16 hh = (f16)uv[i];
      sm.ts.hi[n4 + i][c] = hh;
      sm.ts.lo[n4 + i][c] = (f16)(uv[i] - (float)hh);
    }
  }
  __syncthreads();

  half8 ah[8], al[8];
#pragma unroll
  for (int kc = 0; kc < 8; ++kc) {
    ah[kc] = *reinterpret_cast<const half8*>(&sm.ts.hi[g * 16 + row16][kc * 32 + quad * 8]);
    al[kc] = *reinterpret_cast<const half8*>(&sm.ts.lo[g * 16 + row16][kc * 32 + quad * 8]);
  }
  __syncthreads();

  // ---- q then k: ex reuse is wave-local (each h-wave reads exactly the co-half it wrote) ----
  const f16* WTs[2]    = {wqp, wkp};
  const float* biases[2] = {bq, bk};
  f16* outs[2]         = {qp, kp};
#pragma unroll
  for (int z = 0; z < 2; ++z) {
    const f16* WT = WTs[z];
    const float* bias = biases[z];
    f16* outp = outs[z];
#pragma unroll
    for (int cp = 0; cp < 2; ++cp) {
      f32x4 acch[4], accl[4];
#pragma unroll
      for (int u = 0; u < 4; ++u) { acch[u] = {0.f,0.f,0.f,0.f}; accl[u] = {0.f,0.f,0.f,0.f}; }
#pragma unroll
      for (int kc = 0; kc < 8; ++kc) {
#pragma unroll
        for (int u = 0; u < 4; ++u) {
          int ct = h * 8 + cp * 4 + u;
          half8 b = ldg8(WT + ((size_t)ct * 8 + kc) * 512 + lane * 8);
          acch[u] = __builtin_amdgcn_mfma_f32_16x16x32_f16(ah[kc], b, acch[u], 0, 0, 0);
          accl[u] = __builtin_amdgcn_mfma_f32_16x16x32_f16(al[kc], b, accl[u], 0, 0, 0);
        }
      }
#pragma unroll
      for (int u = 0; u < 4; ++u) {
        int ct = h * 8 + cp * 4 + u;
        int co = ct * 16 + row16;
        float bb = bias[co];
#pragma unroll
        for (int r = 0; r < 4; ++r)
          sm.ex[g][quad * 4 + r][co] = (f16)(acch[u][r] + accl[u][r] + bb);
      }
    }
    // pack to global: wave-local rows/channels of ex
    const f16* exr = &sm.ex[g][row16][0];
    size_t fb = ((size_t)bl * 64 + (n0 >> 4) + g) * 8;
#pragma unroll
    for (int k = 0; k < 4; ++k) {
      int kc = h * 4 + k;
      half8 hv = *reinterpret_cast<const half8*>(exr + kc * 32 + quad * 8);
      *reinterpret_cast<half8*>(outp + (fb + kc) * 512 + lane * 8) = hv;
    }
  }
  __syncthreads();   // all waves done with ex before exv (cross-wave alias) is written

  // ---- v: transposed epilogue into exv, then packed vT store ----
#pragma unroll
  for (int cp = 0; cp < 2; ++cp) {
    f32x4 acch[4], accl[4];
#pragma unroll
    for (int u = 0; u < 4; ++u) { acch[u] = {0.f,0.f,0.f,0.f}; accl[u] = {0.f,0.f,0.f,0.f}; }
#pragma unroll
    for (int kc = 0; kc < 8; ++kc) {
#pragma unroll
      for (int u = 0; u < 4; ++u) {
        int ct = h * 8 + cp * 4 + u;
        half8 b = ldg8(wvp + ((size_t)ct * 8 + kc) * 512 + lane * 8);
        acch[u] = __builtin_amdgcn_mfma_f32_16x16x32_f16(ah[kc], b, acch[u], 0, 0, 0);
        accl[u] = __builtin_amdgcn_mfma_f32_16x16x32_f16(al[kc], b, accl[u], 0, 0, 0);
      }
    }
#pragma unroll
    for (int u = 0; u < 4; ++u) {
      int ct = h * 8 + cp * 4 + u;
      int co = ct * 16 + row16;
      float bb = bv[co];
#pragma unroll
      for (int r = 0; r < 4; ++r)
        sm.exv[co][g * 16 + quad * 4 + r] = (f16)(acch[u][r] + accl[u][r] + bb);
    }
  }
  __syncthreads();
  size_t vb = ((size_t)bl * 32 + blockIdx.y) * 16;
#pragma unroll
  for (int f = 0; f < 4; ++f) {
    int ct = wave * 4 + f;
    half8 o = *reinterpret_cast<const half8*>(&sm.exv[ct * 16 + row16][quad * 8]);
    *reinterpret_cast<half8*>(vp + (vb + ct) * 512 + lane * 8) = o;
  }
}

// ---------------- fused flash attention + MLP(SiLU) + LayerNorm (unchanged from R2) ----------------
// LDS-PIPELINED. grid (nb, 16). block 256 = 4 waves, each owning one 16-row j-tile.
// Block cooperatively stages 128-i Q/V chunks via async global_load_lds, phase-offset
// prefetch, counted vmcnt(16) — loads stay in flight across raw s_barriers.
struct AttnSmem {
  union {
    struct {
      f16 QB[128 * 256];   // 64 KB: packed q frags, current 128-i chunk
      f16 VB[128 * 256];   // 64 KB: packed vT frags, current 128-i chunk
    } s;
    f16 ex[4][16][264];    // epilogue per-wave exchange (att, h)   66 KB
  } u;
  f16 P[4][4][16][40];     // per-wave P round-trip (C->A layout)   20 KB
};

__global__ void __launch_bounds__(256) k_attn_mlp(
    const f16* __restrict__ qp, const f16* __restrict__ kp, const f16* __restrict__ vp,
    const f16* __restrict__ w1p, const float* __restrict__ b1,
    const f16* __restrict__ w2p, const float* __restrict__ b2,
    const float* __restrict__ gamma, const float* __restrict__ beta,
    float* __restrict__ out, int b_base) {
  __shared__ AttnSmem sm;
  int bl = blockIdx.x, bg = b_base + bl;
  int j0 = blockIdx.y * 64;
  int tid = threadIdx.x, wave = tid >> 6, lane = tid & 63;
  int row16 = lane & 15, quad = lane >> 4;
  int jw = j0 + wave * 16;

  const f16* kbase = kp + (size_t)bl * NN * CC;
  int jt = (j0 >> 4) + wave;
  half8 kf[8];
#pragma unroll
  for (int kc = 0; kc < 8; ++kc)
    kf[kc] = ldg8(kbase + ((size_t)jt * 8 + kc) * 512 + lane * 8);

  const f16* qbase = qp + (size_t)bl * NN * CC;
  const f16* vbase = vp + (size_t)bl * CC * NN;

  stage64k(qbase, sm.u.s.QB, wave, lane);
  stage64k(vbase, sm.u.s.VB, wave, lane);
  VMCNT(16);   // kf + Q done, V in flight
  BAR();

  f32x4 O[16];
#pragma unroll
  for (int ct = 0; ct < 16; ++ct) O[ct] = {0.f, 0.f, 0.f, 0.f};
  float m_run[4], l_lane[4];
#pragma unroll
  for (int r = 0; r < 4; ++r) { m_run[r] = -1e30f; l_lane[r] = 0.f; }

  for (int it = 0; it < 8; ++it) {
    f32x4 s[8];
#pragma unroll
    for (int f = 0; f < 8; ++f) s[f] = {0.f, 0.f, 0.f, 0.f};
#pragma unroll
    for (int kc = 0; kc < 8; ++kc) {
#pragma unroll
      for (int f = 0; f < 8; ++f) {
        half8 b = *reinterpret_cast<const half8*>(&sm.u.s.QB[(f * 8 + kc) * 512 + lane * 8]);
        s[f] = __builtin_amdgcn_mfma_f32_16x16x32_f16(kf[kc], b, s[f], 0, 0, 0);
      }
    }
    BAR();                                                    // all waves done reading QB
    stage64k(qbase + (size_t)((it + 1) & 7) * 32768, sm.u.s.QB, wave, lane);

    float alpha[4];
#pragma unroll
    for (int r = 0; r < 4; ++r) {
      float mx = s[0][r];
#pragma unroll
      for (int f = 1; f < 8; ++f) mx = fmaxf(mx, s[f][r]);
#pragma unroll
      for (int off = 1; off < 16; off <<= 1) mx = fmaxf(mx, __shfl_xor(mx, off, 64));
      float mnew = fmaxf(m_run[r], mx);
      alpha[r] = __expf(m_run[r] - mnew);
      m_run[r] = mnew;
      float ps = 0.f;
#pragma unroll
      for (int f = 0; f < 8; ++f) {
        float pv = __expf(s[f][r] - mnew);
        ps += pv;
        sm.P[wave][f >> 1][quad * 4 + r][(f & 1) * 16 + row16] = (f16)pv;
      }
      l_lane[r] = l_lane[r] * alpha[r] + ps;
    }
#pragma unroll
    for (int ct = 0; ct < 16; ++ct)
#pragma unroll
      for (int r = 0; r < 4; ++r) O[ct][r] *= alpha[r];

    VMCNT(16);   // V(it) landed
    BAR();

#pragma unroll
    for (int c4 = 0; c4 < 4; ++c4) {
      half8 pf = *reinterpret_cast<const half8*>(&sm.P[wave][c4][row16][quad * 8]);
#pragma unroll
      for (int ct = 0; ct < 16; ++ct) {
        half8 vf = *reinterpret_cast<const half8*>(&sm.u.s.VB[(c4 * 16 + ct) * 512 + lane * 8]);
        O[ct] = __builtin_amdgcn_mfma_f32_16x16x32_f16(pf, vf, O[ct], 0, 0, 0);
      }
    }
    BAR();                                                    // all waves done reading VB
    stage64k(vbase + (size_t)((it + 1) & 7) * 32768, sm.u.s.VB, wave, lane);
    VMCNT(16);   // Q(it+1) landed
    BAR();
  }
  VMCNT(0);      // drain wrap-around stages before aliasing ex over QB/VB
  BAR();

  float inv[4];
#pragma unroll
  for (int r = 0; r < 4; ++r) {
    float l = l_lane[r];
#pragma unroll
    for (int off = 1; off < 16; off <<= 1) l += __shfl_xor(l, off, 64);
    inv[r] = 1.f / l;
  }

#pragma unroll
  for (int ct = 0; ct < 16; ++ct)
#pragma unroll
    for (int r = 0; r < 4; ++r)
      sm.u.ex[wave][quad * 4 + r][ct * 16 + row16] = (f16)(O[ct][r] * inv[r]);

  half8 af[8];
#pragma unroll
  for (int kc = 0; kc < 8; ++kc)
    af[kc] = *reinterpret_cast<const half8*>(&sm.u.ex[wave][row16][kc * 32 + quad * 8]);

#pragma unroll
  for (int ct = 0; ct < 16; ++ct) {
    f32x4 acc = {0.f, 0.f, 0.f, 0.f};
    const f16* brow = w1p + ((size_t)ct * 8) * 512 + lane * 8;
#pragma unroll
    for (int kc = 0; kc < 8; ++kc)
      acc = __builtin_amdgcn_mfma_f32_16x16x32_f16(af[kc], ldg8(brow + kc * 512), acc, 0, 0, 0);
    int co = ct * 16 + row16;
    float bb = b1[co];
#pragma unroll
    for (int r = 0; r < 4; ++r) {
      float xg = acc[r] + bb;
      float hh = xg / (1.f + __expf(-xg));  // SiLU
      sm.u.ex[wave][quad * 4 + r][co] = (f16)hh;
    }
  }

  half8 hf[8];
#pragma unroll
  for (int kc = 0; kc < 8; ++kc)
    hf[kc] = *reinterpret_cast<const half8*>(&sm.u.ex[wave][row16][kc * 32 + quad * 8]);

  f32x4 acc2[16];
#pragma unroll
  for (int ct = 0; ct < 16; ++ct) {
    f32x4 acc = {0.f, 0.f, 0.f, 0.f};
    const f16* brow = w2p + ((size_t)ct * 8) * 512 + lane * 8;
#pragma unroll
    for (int kc = 0; kc < 8; ++kc)
      acc = __builtin_amdgcn_mfma_f32_16x16x32_f16(hf[kc], ldg8(brow + kc * 512), acc, 0, 0, 0);
    float bb = b2[ct * 16 + row16];
#pragma unroll
    for (int r = 0; r < 4; ++r) acc[r] += bb;
    acc2[ct] = acc;
  }

  float sum[4] = {0.f, 0.f, 0.f, 0.f}, ssq[4] = {0.f, 0.f, 0.f, 0.f};
#pragma unroll
  for (int ct = 0; ct < 16; ++ct)
#pragma unroll
    for (int r = 0; r < 4; ++r) { float xv = acc2[ct][r]; sum[r] += xv; ssq[r] += xv * xv; }
  float mean[4], rstd[4];
#pragma unroll
  for (int r = 0; r < 4; ++r) {
#pragma unroll
    for (int off = 1; off < 16; off <<= 1) {
      sum[r] += __shfl_xor(sum[r], off, 64);
      ssq[r] += __shfl_xor(ssq[r], off, 64);
    }
    mean[r] = sum[r] * (1.f / 256.f);
    float var = ssq[r] * (1.f / 256.f) - mean[r] * mean[r];
    rstd[r] = rsqrtf(var + 1e-5f);
  }

#pragma unroll
  for (int ct = 0; ct < 16; ++ct) {
    int col = ct * 16 + row16;
    float g = gamma[col], be = beta[col];
    f32x4 v;
#pragma unroll
    for (int r = 0; r < 4; ++r) v[r] = (acc2[ct][r] - mean[r]) * rstd[r] * g + be;
    *reinterpret_cast<f32x4*>(out + (size_t)(bg * CC + col) * NN + jw + quad * 4) = v;
  }
}

extern "C" void kernel_launch(void* const* d_in, const int* in_sizes, int n_in,
                              void* d_out, int out_size, void* d_ws, size_t ws_size,
                              hipStream_t stream) {
  (void)in_sizes; (void)n_in; (void)out_size;
  const float* x     = (const float*)d_in[0];
  const float* wq    = (const float*)d_in[1];
  const float* bq    = (const float*)d_in[2];
  const float* wk    = (const float*)d_in[3];
  const float* bk    = (const float*)d_in[4];
  const float* wv    = (const float*)d_in[5];
  const float* bv    = (const float*)d_in[6];
  const float* w1    = (const float*)d_in[7];
  const float* b1    = (const float*)d_in[8];
  const float* w2    = (const float*)d_in[9];
  const float* b2    = (const float*)d_in[10];
  const float* gamma = (const float*)d_in[11];
  const float* beta  = (const float*)d_in[12];
  float* out = (float*)d_out;

  const size_t WE = 65536;
  const size_t SB = (size_t)NN * CC;
  f16* base = (f16*)d_ws;
  f16* wqp = base + 0 * WE;
  f16* wkp = base + 1 * WE;
  f16* wvp = base + 2 * WE;
  f16* w1p = base + 3 * WE;
  f16* w2p = base + 4 * WE;

  size_t wbytes = 5 * WE * sizeof(f16);
  size_t perb   = 3 * SB * sizeof(f16);
  int nb = (ws_size > wbytes) ? (int)((ws_size - wbytes) / perb) : 1;
  if (nb < 1) nb = 1;
  if (nb > BB) nb = BB;

  f16* qb  = base + 5 * WE;
  f16* kb  = qb + (size_t)nb * SB;
  f16* vTb = kb + (size_t)nb * SB;

  WP5 p;
  p.s[0] = wq; p.s[1] = wk; p.s[2] = wv; p.s[3] = w1; p.s[4] = w2;
  p.d[0] = wqp; p.d[1] = wkp; p.d[2] = wvp; p.d[3] = w1p; p.d[4] = w2p;
  k_packW<<<dim3(16, 5), 256, 0, stream>>>(p);

  for (int b0 = 0; b0 < BB; b0 += nb) {
    int cb = (b0 + nb <= BB) ? nb : (BB - b0);
    k_qkv<<<dim3(cb, 32), 256, 0, stream>>>(x, wqp, wkp, wvp, bq, bk, bv, qb, kb, vTb, b0);
    k_attn_mlp<<<dim3(cb, 16), 256, 0, stream>>>(qb, kb, vTb, w1p, b1, w2p, b2,
                                                 gamma, beta, out, b0);
  }
}

// Round 4
// 176.558 us; speedup vs baseline: 1.6164x; 1.1306x over previous
//
#include <hip/hip_runtime.h>

#define BB 16
#define CC 256
#define NN 1024

typedef _Float16 f16;
typedef __attribute__((ext_vector_type(8))) _Float16 half8;   // MFMA A/B frag (4 VGPRs)
typedef __attribute__((ext_vector_type(4))) float f32x4;      // MFMA C/D frag

__device__ __forceinline__ half8 ldg8(const f16* p) {
  return *reinterpret_cast<const half8*>(p);
}

// async global->LDS, 16B per lane; lds base must be wave-uniform (HW adds lane*16)
__device__ __forceinline__ void gll16(const f16* g, f16* l) {
  __builtin_amdgcn_global_load_lds((const __attribute__((address_space(1))) void*)g,
                                   (__attribute__((address_space(3))) void*)l, 16, 0, 0);
}

#define VMCNT(n) asm volatile("s_waitcnt vmcnt(" #n ")" ::: "memory")
#define BAR() __builtin_amdgcn_s_barrier()

// stage one contiguous 64 KB chunk (32768 f16) with 256 threads: 16 issues/thread.
__device__ __forceinline__ void stage64k(const f16* __restrict__ g, f16* l, int wave, int lane) {
#pragma unroll
  for (int k = 0; k < 16; ++k) {
    int ob = k * 2048 + wave * 512;      // wave-uniform f16 offset
    gll16(g + ob + lane * 8, l + ob);
  }
}

// stage one contiguous 64 KB chunk with 512 threads (8 waves): 8 issues/thread.
__device__ __forceinline__ void stage64k8(const f16* __restrict__ g, f16* l, int wave, int lane) {
#pragma unroll
  for (int k = 0; k < 8; ++k) {
    int ob = k * 4096 + wave * 512;      // 8 waves x 512 = 4096 per k
    gll16(g + ob + lane * 8, l + ob);
  }
}

// ---------------- weight pack: W fp32 [ci][co] -> frag-packed f16 wp[(ct*8+kc)*512 + lane*8] ----
struct WP5 {
  const float* s[5];
  f16* d[5];
};

__global__ void __launch_bounds__(256) k_packW(WP5 p) {
  __shared__ float ws[256][17];
  int m = blockIdx.y, ct = blockIdx.x;
  const float* W = p.s[m];
  f16* wp = p.d[m];
  int tid = threadIdx.x;
  int col = tid & 15, cig = tid >> 4;
#pragma unroll
  for (int pg = 0; pg < 16; ++pg) {
    int ci = pg * 16 + cig;
    ws[ci][col] = W[(size_t)ci * 256 + ct * 16 + col];
  }
  __syncthreads();
  int lane = tid & 63, wave = tid >> 6;
  int row16 = lane & 15, quad = lane >> 4;
#pragma unroll
  for (int kk = 0; kk < 2; ++kk) {
    int kc = wave * 2 + kk;
    half8 o;
#pragma unroll
    for (int j = 0; j < 8; ++j) o[j] = (f16)ws[kc * 32 + quad * 8 + j][row16];
    *reinterpret_cast<half8*>(wp + ((size_t)ct * 8 + kc) * 512 + lane * 8) = o;
  }
}

// ---------------- QKV (z-merged, unchanged from R3) ----------------
struct QkvSmem {
  union {
    struct { f16 hi[32][264]; f16 lo[32][264]; } ts;
    f16 ex[2][16][264];
    f16 exv[256][40];
  };
};

__global__ void __launch_bounds__(256) k_qkv(const float* __restrict__ x,
    const f16* __restrict__ wqp, const f16* __restrict__ wkp, const f16* __restrict__ wvp,
    const float* __restrict__ bq, const float* __restrict__ bk, const float* __restrict__ bv,
    f16* __restrict__ qp, f16* __restrict__ kp, f16* __restrict__ vp, int b_base) {
  __shared__ QkvSmem sm;
  int bl = blockIdx.x, bg = b_base + bl, n0 = blockIdx.y * 32;
  int tid = threadIdx.x, wave = tid >> 6, lane = tid & 63;
  int row16 = lane & 15, quad = lane >> 4;
  int g = wave >> 1, h = wave & 1;

#pragma unroll
  for (int e = tid; e < 2048; e += 256) {
    int c = e >> 3, n4 = (e & 7) << 2;
    float4 u = *reinterpret_cast<const float4*>(x + (size_t)(bg * CC + c) * NN + n0 + n4);
    float uv[4] = {u.x, u.y, u.z, u.w};
#pragma unroll
    for (int i = 0; i < 4; ++i) {
      f16 hh = (f16)uv[i];
      sm.ts.hi[n4 + i][c] = hh;
      sm.ts.lo[n4 + i][c] = (f16)(uv[i] - (float)hh);
    }
  }
  __syncthreads();

  half8 ah[8], al[8];
#pragma unroll
  for (int kc = 0; kc < 8; ++kc) {
    ah[kc] = *reinterpret_cast<const half8*>(&sm.ts.hi[g * 16 + row16][kc * 32 + quad * 8]);
    al[kc] = *reinterpret_cast<const half8*>(&sm.ts.lo[g * 16 + row16][kc * 32 + quad * 8]);
  }
  __syncthreads();

  const f16* WTs[2]    = {wqp, wkp};
  const float* biases[2] = {bq, bk};
  f16* outs[2]         = {qp, kp};
#pragma unroll
  for (int z = 0; z < 2; ++z) {
    const f16* WT = WTs[z];
    const float* bias = biases[z];
    f16* outp = outs[z];
#pragma unroll
    for (int cp = 0; cp < 2; ++cp) {
      f32x4 acch[4], accl[4];
#pragma unroll
      for (int u = 0; u < 4; ++u) { acch[u] = {0.f,0.f,0.f,0.f}; accl[u] = {0.f,0.f,0.f,0.f}; }
#pragma unroll
      for (int kc = 0; kc < 8; ++kc) {
#pragma unroll
        for (int u = 0; u < 4; ++u) {
          int ct = h * 8 + cp * 4 + u;
          half8 b = ldg8(WT + ((size_t)ct * 8 + kc) * 512 + lane * 8);
          acch[u] = __builtin_amdgcn_mfma_f32_16x16x32_f16(ah[kc], b, acch[u], 0, 0, 0);
          accl[u] = __builtin_amdgcn_mfma_f32_16x16x32_f16(al[kc], b, accl[u], 0, 0, 0);
        }
      }
#pragma unroll
      for (int u = 0; u < 4; ++u) {
        int ct = h * 8 + cp * 4 + u;
        int co = ct * 16 + row16;
        float bb = bias[co];
#pragma unroll
        for (int r = 0; r < 4; ++r)
          sm.ex[g][quad * 4 + r][co] = (f16)(acch[u][r] + accl[u][r] + bb);
      }
    }
    const f16* exr = &sm.ex[g][row16][0];
    size_t fb = ((size_t)bl * 64 + (n0 >> 4) + g) * 8;
#pragma unroll
    for (int k = 0; k < 4; ++k) {
      int kc = h * 4 + k;
      half8 hv = *reinterpret_cast<const half8*>(exr + kc * 32 + quad * 8);
      *reinterpret_cast<half8*>(outp + (fb + kc) * 512 + lane * 8) = hv;
    }
  }
  __syncthreads();

#pragma unroll
  for (int cp = 0; cp < 2; ++cp) {
    f32x4 acch[4], accl[4];
#pragma unroll
    for (int u = 0; u < 4; ++u) { acch[u] = {0.f,0.f,0.f,0.f}; accl[u] = {0.f,0.f,0.f,0.f}; }
#pragma unroll
    for (int kc = 0; kc < 8; ++kc) {
#pragma unroll
      for (int u = 0; u < 4; ++u) {
        int ct = h * 8 + cp * 4 + u;
        half8 b = ldg8(wvp + ((size_t)ct * 8 + kc) * 512 + lane * 8);
        acch[u] = __builtin_amdgcn_mfma_f32_16x16x32_f16(ah[kc], b, acch[u], 0, 0, 0);
        accl[u] = __builtin_amdgcn_mfma_f32_16x16x32_f16(al[kc], b, accl[u], 0, 0, 0);
      }
    }
#pragma unroll
    for (int u = 0; u < 4; ++u) {
      int ct = h * 8 + cp * 4 + u;
      int co = ct * 16 + row16;
      float bb = bv[co];
#pragma unroll
      for (int r = 0; r < 4; ++r)
        sm.exv[co][g * 16 + quad * 4 + r] = (f16)(acch[u][r] + accl[u][r] + bb);
    }
  }
  __syncthreads();
  size_t vb = ((size_t)bl * 32 + blockIdx.y) * 16;
#pragma unroll
  for (int f = 0; f < 4; ++f) {
    int ct = wave * 4 + f;
    half8 o = *reinterpret_cast<const half8*>(&sm.exv[ct * 16 + row16][quad * 8]);
    *reinterpret_cast<half8*>(vp + (vb + ct) * 512 + lane * 8) = o;
  }
}

// ---------------- fused flash attention + MLP(SiLU) + LayerNorm ----------------
// 8-WAVE PARITY i-SPLIT. grid (nb, 16). block 512 = 8 waves: wave w and w^4 own the same
// 16-row j-tile (jt = w&3) but process even/odd 64-i chunks (parity p = w>>2) with
// independent online-softmax states. Both parities' chunks are co-resident in LDS
// (QB[2]/VB[2]); all 8 waves cooperatively stage the next pair via async global_load_lds
// with counted vmcnt(8) (never drained in-loop). This doubles waves/SIMD (1 -> 2) at
// IDENTICAL staging traffic: the measured R3 state (80 us, MfmaUtil 10%, occupancy 10.4%,
// 3.2 TB/s L2 = 9% of ceiling) is latency-exposure at 1 wave/SIMD, not bandwidth.
// Epilogue: pairwise (m,l,O) combine via f32 LDS buffer aliased over dead QB (no atomics);
// MLP + LN split ct-halves across the wave pair.
struct AttnSmem {
  union {
    struct {
      f16 QB[2][64 * 256];   // 2 x 32 KB: packed q frags, chunk parity 0/1
      f16 VB[2][64 * 256];   // 2 x 32 KB: packed vT frags
    } s;
    struct {
      union {
        float Ocmb[4][16][260];   // 66.6 KB: pairwise O-combine (f32)
        f16 ex2[4][16][264];      // 33 KB: MLP hidden h (aliases Ocmb, used after)
      } a;
      f16 ex[4][16][264];         // 33 KB: normalized att per j-tile
    } e;
  } u;                        // 128 KB
  f16 P[8][2][16][40];        // per-wave P round-trip (C->A layout)   20.5 KB
  float ml[8][2][16];         // per-wave {m, l} per j-row              1 KB
  float lnbuf[8][2][16];      // per-wave LN partials {sum, ssq}        1 KB
};

__global__ void __launch_bounds__(512, 2) k_attn_mlp(
    const f16* __restrict__ qp, const f16* __restrict__ kp, const f16* __restrict__ vp,
    const f16* __restrict__ w1p, const float* __restrict__ b1,
    const f16* __restrict__ w2p, const float* __restrict__ b2,
    const float* __restrict__ gamma, const float* __restrict__ beta,
    float* __restrict__ out, int b_base) {
  __shared__ AttnSmem sm;
  int bl = blockIdx.x, bg = b_base + bl;
  int j0 = blockIdx.y * 64;
  int tid = threadIdx.x, wave = tid >> 6, lane = tid & 63;
  int row16 = lane & 15, quad = lane >> 4;
  int jt_l = wave & 3, p = wave >> 2;        // j-tile within block, i-chunk parity
  int jw = j0 + jt_l * 16;

  // A-frags: k rows of this wave's j-tile (partner waves load the same rows; L2-hot)
  const f16* kbase = kp + (size_t)bl * NN * CC;
  int jt = (j0 >> 4) + jt_l;
  half8 kf[8];
#pragma unroll
  for (int kc = 0; kc < 8; ++kc)
    kf[kc] = ldg8(kbase + ((size_t)jt * 8 + kc) * 512 + lane * 8);

  const f16* qbase = qp + (size_t)bl * NN * CC;
  const f16* vbase = vp + (size_t)bl * CC * NN;

  // prologue: stage chunk pair 0 (chunks 0,1 = 64 KB) of Q and V
  stage64k8(qbase, &sm.u.s.QB[0][0], wave, lane);
  stage64k8(vbase, &sm.u.s.VB[0][0], wave, lane);
  VMCNT(8);   // kf(8) + Q(8) drained, V(8) in flight
  BAR();

  f32x4 O[16];
#pragma unroll
  for (int ct = 0; ct < 16; ++ct) O[ct] = {0.f, 0.f, 0.f, 0.f};
  float m_run[4], l_lane[4];
#pragma unroll
  for (int r = 0; r < 4; ++r) { m_run[r] = -1e30f; l_lane[r] = 0.f; }

  const f16* QBp = &sm.u.s.QB[p][0];
  const f16* VBp = &sm.u.s.VB[p][0];

  for (int it = 0; it < 8; ++it) {
    // ---- QK: scores S[16 j][64 i] from LDS, 4 parallel MFMA chains ----
    f32x4 s[4];
#pragma unroll
    for (int f = 0; f < 4; ++f) s[f] = {0.f, 0.f, 0.f, 0.f};
#pragma unroll
    for (int kc = 0; kc < 8; ++kc) {
#pragma unroll
      for (int f = 0; f < 4; ++f) {
        half8 b = *reinterpret_cast<const half8*>(&QBp[(f * 8 + kc) * 512 + lane * 8]);
        s[f] = __builtin_amdgcn_mfma_f32_16x16x32_f16(kf[kc], b, s[f], 0, 0, 0);
      }
    }
    BAR();                                                    // all waves done reading QB
    stage64k8(qbase + (size_t)((it + 1) & 7) * 32768, &sm.u.s.QB[0][0], wave, lane);

    // ---- softmax per j-row over this wave's 64 i (overlaps Q staging) ----
    float alpha[4];
#pragma unroll
    for (int r = 0; r < 4; ++r) {
      float mx = s[0][r];
#pragma unroll
      for (int f = 1; f < 4; ++f) mx = fmaxf(mx, s[f][r]);
#pragma unroll
      for (int off = 1; off < 16; off <<= 1) mx = fmaxf(mx, __shfl_xor(mx, off, 64));
      float mnew = fmaxf(m_run[r], mx);
      alpha[r] = __expf(m_run[r] - mnew);
      m_run[r] = mnew;
      float ps = 0.f;
#pragma unroll
      for (int f = 0; f < 4; ++f) {
        float pv = __expf(s[f][r] - mnew);
        ps += pv;
        sm.P[wave][f >> 1][quad * 4 + r][(f & 1) * 16 + row16] = (f16)pv;
      }
      l_lane[r] = l_lane[r] * alpha[r] + ps;
    }
#pragma unroll
    for (int ct = 0; ct < 16; ++ct)
#pragma unroll
      for (int r = 0; r < 4; ++r) O[ct][r] *= alpha[r];

    VMCNT(8);    // V(it) landed (only next-Q's 8 remain in flight)
    BAR();       // all waves' V(it) visible

    // ---- PV: 2 chunks of 32 i; P same-wave LDS round-trip, vT frags from LDS ----
#pragma unroll
    for (int c4 = 0; c4 < 2; ++c4) {
      half8 pf = *reinterpret_cast<const half8*>(&sm.P[wave][c4][row16][quad * 8]);
#pragma unroll
      for (int ct = 0; ct < 16; ++ct) {
        half8 vf = *reinterpret_cast<const half8*>(&VBp[(c4 * 16 + ct) * 512 + lane * 8]);
        O[ct] = __builtin_amdgcn_mfma_f32_16x16x32_f16(pf, vf, O[ct], 0, 0, 0);
      }
    }
    BAR();                                                    // all waves done reading VB
    stage64k8(vbase + (size_t)((it + 1) & 7) * 32768, &sm.u.s.VB[0][0], wave, lane);
    VMCNT(8);    // Q(it+1) landed (only next-V's 8 remain)
    BAR();
  }
  VMCNT(0);      // drain wrap-around stages before aliasing epilogue over QB/VB
  BAR();

  // ---- pairwise (m, l, O) combine across parity waves ----
#pragma unroll
  for (int r = 0; r < 4; ++r) {
#pragma unroll
    for (int off = 1; off < 16; off <<= 1) l_lane[r] += __shfl_xor(l_lane[r], off, 64);
  }
  if (row16 == 0) {
#pragma unroll
    for (int r = 0; r < 4; ++r) {
      sm.ml[wave][0][quad * 4 + r] = m_run[r];
      sm.ml[wave][1][quad * 4 + r] = l_lane[r];
    }
  }
  BAR();

  int partner = wave ^ 4;
  float alphaS[4], invL[4];
#pragma unroll
  for (int r = 0; r < 4; ++r) {
    int j = quad * 4 + r;
    float ma = m_run[r], mb = sm.ml[partner][0][j];
    float M = fmaxf(ma, mb);
    float la = l_lane[r], lb = sm.ml[partner][1][j];
    float L = la * __expf(ma - M) + lb * __expf(mb - M);
    alphaS[r] = __expf(ma - M);
    invL[r] = 1.f / L;
  }
#pragma unroll
  for (int ct = 0; ct < 16; ++ct)
#pragma unroll
    for (int r = 0; r < 4; ++r) O[ct][r] *= alphaS[r];

  if (p == 1) {
#pragma unroll
    for (int ct = 0; ct < 16; ++ct)
#pragma unroll
      for (int r = 0; r < 4; ++r)
        sm.u.e.a.Ocmb[jt_l][quad * 4 + r][ct * 16 + row16] = O[ct][r];
  }
  BAR();
  if (p == 0) {
#pragma unroll
    for (int ct = 0; ct < 16; ++ct)
#pragma unroll
      for (int r = 0; r < 4; ++r) {
        float v = O[ct][r] + sm.u.e.a.Ocmb[jt_l][quad * 4 + r][ct * 16 + row16];
        sm.u.e.ex[jt_l][quad * 4 + r][ct * 16 + row16] = (f16)(v * invL[r]);
      }
  }
  BAR();   // att tile ready (and Ocmb reads done -> ex2 alias safe)

  // ---- MLP + LN, ct-halves split across the wave pair ----
  half8 af[8];
#pragma unroll
  for (int kc = 0; kc < 8; ++kc)
    af[kc] = *reinterpret_cast<const half8*>(&sm.u.e.ex[jt_l][row16][kc * 32 + quad * 8]);

  // GEMM1: h = silu(att @ w1 + b1) -> ex2 (this wave's 8 ct)
#pragma unroll
  for (int q8 = 0; q8 < 8; ++q8) {
    int ct = p * 8 + q8;
    f32x4 acc = {0.f, 0.f, 0.f, 0.f};
    const f16* brow = w1p + ((size_t)ct * 8) * 512 + lane * 8;
#pragma unroll
    for (int kc = 0; kc < 8; ++kc)
      acc = __builtin_amdgcn_mfma_f32_16x16x32_f16(af[kc], ldg8(brow + kc * 512), acc, 0, 0, 0);
    int co = ct * 16 + row16;
    float bb = b1[co];
#pragma unroll
    for (int r = 0; r < 4; ++r) {
      float xg = acc[r] + bb;
      float hh = xg / (1.f + __expf(-xg));  // SiLU
      sm.u.e.a.ex2[jt_l][quad * 4 + r][co] = (f16)hh;
    }
  }
  BAR();   // full h tile ready

  half8 hf[8];
#pragma unroll
  for (int kc = 0; kc < 8; ++kc)
    hf[kc] = *reinterpret_cast<const half8*>(&sm.u.e.a.ex2[jt_l][row16][kc * 32 + quad * 8]);

  f32x4 acc2[8];
#pragma unroll
  for (int q8 = 0; q8 < 8; ++q8) {
    int ct = p * 8 + q8;
    f32x4 acc = {0.f, 0.f, 0.f, 0.f};
    const f16* brow = w2p + ((size_t)ct * 8) * 512 + lane * 8;
#pragma unroll
    for (int kc = 0; kc < 8; ++kc)
      acc = __builtin_amdgcn_mfma_f32_16x16x32_f16(hf[kc], ldg8(brow + kc * 512), acc, 0, 0, 0);
    float bb = b2[ct * 16 + row16];
#pragma unroll
    for (int r = 0; r < 4; ++r) acc[r] += bb;
    acc2[q8] = acc;
  }

  // LayerNorm over C: per-wave partials (128 channels) + pairwise LDS exchange
  float sum[4] = {0.f, 0.f, 0.f, 0.f}, ssq[4] = {0.f, 0.f, 0.f, 0.f};
#pragma unroll
  for (int q8 = 0; q8 < 8; ++q8)
#pragma unroll
    for (int r = 0; r < 4; ++r) { float xv = acc2[q8][r]; sum[r] += xv; ssq[r] += xv * xv; }
#pragma unroll
  for (int r = 0; r < 4; ++r) {
#pragma unroll
    for (int off = 1; off < 16; off <<= 1) {
      sum[r] += __shfl_xor(sum[r], off, 64);
      ssq[r] += __shfl_xor(ssq[r], off, 64);
    }
  }
  if (row16 == 0) {
#pragma unroll
    for (int r = 0; r < 4; ++r) {
      sm.lnbuf[wave][0][quad * 4 + r] = sum[r];
      sm.lnbuf[wave][1][quad * 4 + r] = ssq[r];
    }
  }
  BAR();

  float mean[4], rstd[4];
#pragma unroll
  for (int r = 0; r < 4; ++r) {
    int j = quad * 4 + r;
    float s = sm.lnbuf[wave][0][j] + sm.lnbuf[partner][0][j];
    float sq = sm.lnbuf[wave][1][j] + sm.lnbuf[partner][1][j];
    mean[r] = s * (1.f / 256.f);
    float var = sq * (1.f / 256.f) - mean[r] * mean[r];
    rstd[r] = rsqrtf(var + 1e-5f);
  }

  // coalesced nontemporal stores: this wave's 128 channels
#pragma unroll
  for (int q8 = 0; q8 < 8; ++q8) {
    int col = (p * 8 + q8) * 16 + row16;
    float g = gamma[col], be = beta[col];
    f32x4 v;
#pragma unroll
    for (int r = 0; r < 4; ++r) v[r] = (acc2[q8][r] - mean[r]) * rstd[r] * g + be;
    __builtin_nontemporal_store(v,
        reinterpret_cast<f32x4*>(out + (size_t)(bg * CC + col) * NN + jw + quad * 4));
  }
}

extern "C" void kernel_launch(void* const* d_in, const int* in_sizes, int n_in,
                              void* d_out, int out_size, void* d_ws, size_t ws_size,
                              hipStream_t stream) {
  (void)in_sizes; (void)n_in; (void)out_size;
  const float* x     = (const float*)d_in[0];
  const float* wq    = (const float*)d_in[1];
  const float* bq    = (const float*)d_in[2];
  const float* wk    = (const float*)d_in[3];
  const float* bk    = (const float*)d_in[4];
  const float* wv    = (const float*)d_in[5];
  const float* bv    = (const float*)d_in[6];
  const float* w1    = (const float*)d_in[7];
  const float* b1    = (const float*)d_in[8];
  const float* w2    = (const float*)d_in[9];
  const float* b2    = (const float*)d_in[10];
  const float* gamma = (const float*)d_in[11];
  const float* beta  = (const float*)d_in[12];
  float* out = (float*)d_out;

  const size_t WE = 65536;
  const size_t SB = (size_t)NN * CC;
  f16* base = (f16*)d_ws;
  f16* wqp = base + 0 * WE;
  f16* wkp = base + 1 * WE;
  f16* wvp = base + 2 * WE;
  f16* w1p = base + 3 * WE;
  f16* w2p = base + 4 * WE;

  size_t wbytes = 5 * WE * sizeof(f16);
  size_t perb   = 3 * SB * sizeof(f16);
  int nb = (ws_size > wbytes) ? (int)((ws_size - wbytes) / perb) : 1;
  if (nb < 1) nb = 1;
  if (nb > BB) nb = BB;

  f16* qb  = base + 5 * WE;
  f16* kb  = qb + (size_t)nb * SB;
  f16* vTb = kb + (size_t)nb * SB;

  WP5 p;
  p.s[0] = wq; p.s[1] = wk; p.s[2] = wv; p.s[3] = w1; p.s[4] = w2;
  p.d[0] = wqp; p.d[1] = wkp; p.d[2] = wvp; p.d[3] = w1p; p.d[4] = w2p;
  k_packW<<<dim3(16, 5), 256, 0, stream>>>(p);

  for (int b0 = 0; b0 < BB; b0 += nb) {
    int cb = (b0 + nb <= BB) ? nb : (BB - b0);
    k_qkv<<<dim3(cb, 32), 256, 0, stream>>>(x, wqp, wkp, wvp, bq, bk, bv, qb, kb, vTb, b0);
    k_attn_mlp<<<dim3(cb, 16), 512, 0, stream>>>(qb, kb, vTb, w1p, b1, w2p, b2,
                                                 gamma, beta, out, b0);
  }
}